// Round 11
// baseline (548.109 us; speedup 1.0000x reference)
//
#include <hip/hip_runtime.h>

#define SEQ 4096
#define KDIM 1024
#define NQKV 3072
#define BK 32

#define N_QVK   768
#define N_SCORE 528
#define N_PV    640
#define N_TOTAL (N_QVK + N_SCORE + N_PV)

typedef __bf16 bf16x8 __attribute__((ext_vector_type(8)));
typedef float  f32x4  __attribute__((ext_vector_type(4)));

__device__ __forceinline__ unsigned short f2b(float f) {
    unsigned int u = __float_as_uint(f);
    u += 0x7FFFu + ((u >> 16) & 1u);   // round-to-nearest-even
    return (unsigned short)(u >> 16);
}

__device__ __forceinline__ void gld_lds16(const unsigned short* g, unsigned short* l) {
    __builtin_amdgcn_global_load_lds(
        (const __attribute__((address_space(1))) void*)g,
        (__attribute__((address_space(3))) void*)l, 16, 0, 0);
}

// ---------------------------------------------------------------------------
// R4-proven 128x128x32 tile loop: 4 waves 2x2, XOR-swizzled LDS, 2-stage
// __syncthreads double-buffer (32 KB). Unchanged — R5-R10 bracketed this as
// the local optimum (deeper pipes, smaller tiles, LDS-free all regress).
// ---------------------------------------------------------------------------
__device__ __forceinline__ void stage_tiles(
    const unsigned short* Ag, int lda, const unsigned short* Bg, int ldb,
    int k0, unsigned short* sA, unsigned short* sB, int wave, int lane)
{
    #pragma unroll
    for (int i = 0; i < 2; ++i) {
        int c = wave * 128 + i * 64 + lane;
        int row = c >> 2, slot = c & 3;
        int p = slot ^ ((row >> 1) & 3);
        gld_lds16(Ag + row * lda + k0 + p * 8, sA + (wave * 2 + i) * 512);
        gld_lds16(Bg + row * ldb + k0 + p * 8, sB + (wave * 2 + i) * 512);
    }
}

__device__ __forceinline__ const unsigned short* frag_addr(
    const unsigned short* s, int row, int quad)
{
    return s + row * 32 + (quad ^ ((row >> 1) & 3)) * 8;
}

__device__ __forceinline__ void compute_tile(
    const unsigned short* sA, const unsigned short* sB, f32x4 acc[4][4],
    int wm, int wn, int lr, int quad)
{
    bf16x8 af[4], bq[4];
    #pragma unroll
    for (int i = 0; i < 4; ++i)
        af[i] = *(const bf16x8*)frag_addr(sA, wm + 16 * i + lr, quad);
    #pragma unroll
    for (int j = 0; j < 4; ++j)
        bq[j] = *(const bf16x8*)frag_addr(sB, wn + 16 * j + lr, quad);
    #pragma unroll
    for (int i = 0; i < 4; ++i)
        #pragma unroll
        for (int j = 0; j < 4; ++j)
            acc[i][j] = __builtin_amdgcn_mfma_f32_16x16x32_bf16(af[i], bq[j], acc[i][j], 0, 0, 0);
}

__device__ __forceinline__ void mfma_db(
    const unsigned short* Ag, int lda, const unsigned short* Bg, int ldb,
    int kLen, unsigned short* lds, f32x4 acc[4][4])
{
    const int tid  = threadIdx.x;
    const int wave = tid >> 6, lane = tid & 63;
    const int lr   = lane & 15, quad = lane >> 4;
    const int wm   = (wave >> 1) * 64, wn = (wave & 1) * 64;
    unsigned short* sA0 = lds;
    unsigned short* sB0 = lds + 4096;
    unsigned short* sA1 = lds + 8192;
    unsigned short* sB1 = lds + 12288;

    stage_tiles(Ag, lda, Bg, ldb, 0, sA0, sB0, wave, lane);
    int k = BK;
    #pragma unroll 1
    for (; k + BK < kLen; k += 2 * BK) {
        __syncthreads();
        stage_tiles(Ag, lda, Bg, ldb, k, sA1, sB1, wave, lane);
        compute_tile(sA0, sB0, acc, wm, wn, lr, quad);
        __syncthreads();
        stage_tiles(Ag, lda, Bg, ldb, k + BK, sA0, sB0, wave, lane);
        compute_tile(sA1, sB1, acc, wm, wn, lr, quad);
    }
    if (k < kLen) {
        __syncthreads();
        stage_tiles(Ag, lda, Bg, ldb, k, sA1, sB1, wave, lane);
        compute_tile(sA0, sB0, acc, wm, wn, lr, quad);
        __syncthreads();
        compute_tile(sA1, sB1, acc, wm, wn, lr, quad);
    } else {
        __syncthreads();
        compute_tile(sA0, sB0, acc, wm, wn, lr, quad);
    }
}

__device__ __forceinline__ void zero_acc(f32x4 acc[4][4]) {
    const f32x4 z = {0.f, 0.f, 0.f, 0.f};
    #pragma unroll
    for (int i = 0; i < 4; ++i)
        #pragma unroll
        for (int j = 0; j < 4; ++j) acc[i][j] = z;
}

// ---------------------------------------------------------------------------
// Epilogues: wave-private LDS restage -> 16B coalesced bf16 stores.
// ---------------------------------------------------------------------------
__device__ __forceinline__ void store_rows_bf16(
    f32x4 acc[4][4], unsigned short* Cw, int ld, unsigned short* lw, int lane)
{
    const int lr = lane & 15, quad = lane >> 4;
    #pragma unroll
    for (int i = 0; i < 4; ++i) {
        #pragma unroll
        for (int j = 0; j < 4; ++j)
            #pragma unroll
            for (int r = 0; r < 4; ++r)
                lw[(quad * 4 + r) * 72 + j * 16 + lr] = f2b(acc[i][j][r]);
        #pragma unroll
        for (int t = 0; t < 2; ++t) {
            int chunk = t * 64 + lane;
            int rl = chunk >> 3, c8 = chunk & 7;
            uint4 v = *(const uint4*)(lw + rl * 72 + c8 * 8);
            *(uint4*)(Cw + (16 * i + rl) * ld + c8 * 8) = v;
        }
    }
}

__device__ __forceinline__ void store_cols_bf16(
    f32x4 acc[4][4], unsigned short* Vw, unsigned short* lw, int lane)
{
    const int lr = lane & 15, quad = lane >> 4;
    #pragma unroll
    for (int ip = 0; ip < 2; ++ip) {
        #pragma unroll
        for (int ii = 0; ii < 2; ++ii)
            #pragma unroll
            for (int j = 0; j < 4; ++j)
                #pragma unroll
                for (int r = 0; r < 4; ++r)
                    lw[(j * 16 + lr) * 40 + ii * 16 + quad * 4 + r] = f2b(acc[ip * 2 + ii][j][r]);
        #pragma unroll
        for (int t = 0; t < 4; ++t) {
            int chunk = t * 64 + lane;
            int col = chunk >> 2, c8 = chunk & 3;
            uint4 v = *(const uint4*)(lw + col * 40 + c8 * 8);
            *(uint4*)(Vw + col * SEQ + ip * 32 + c8 * 8) = v;
        }
    }
}

// ---------------------------------------------------------------------------
// Kernel 0: fused prep. [0,4096): x->bf16; [4096,8192): zero d_out;
// [8192,11264): W transpose (ushort4 stores); block 11264: zero lrow + ctrs.
// ---------------------------------------------------------------------------
__global__ __launch_bounds__(256) void prep(
    const float* __restrict__ x, unsigned short* __restrict__ Xb,
    const float* __restrict__ W, unsigned short* __restrict__ Wt,
    float4* __restrict__ out, float4* __restrict__ lrow, int* __restrict__ ctr)
{
    __shared__ float tile[32][33];
    const int b = blockIdx.x, tid = threadIdx.x;
    if (b < 4096) {
        int i = (b * 256 + tid) * 4;
        float4 v = *(const float4*)(x + i);
        ushort4 o;
        o.x = f2b(v.x); o.y = f2b(v.y); o.z = f2b(v.z); o.w = f2b(v.w);
        *(ushort4*)(Xb + i) = o;
    } else if (b < 8192) {
        const float4 z = {0.f, 0.f, 0.f, 0.f};
        out[(b - 4096) * 256 + tid] = z;
    } else if (b < 11264) {
        const int bb = b - 8192;
        const int n0 = (bb % 96) * 32, k0 = (bb / 96) * 32;
        const int c = tid & 31, r0 = tid >> 5;
        #pragma unroll
        for (int r = r0; r < 32; r += 8)
            tile[r][c] = W[(k0 + r) * NQKV + n0 + c];
        __syncthreads();
        const int n = tid >> 3, q = tid & 7;
        ushort4 o;
        o.x = f2b(tile[q * 4 + 0][n]);
        o.y = f2b(tile[q * 4 + 1][n]);
        o.z = f2b(tile[q * 4 + 2][n]);
        o.w = f2b(tile[q * 4 + 3][n]);
        *(ushort4*)(Wt + (n0 + n) * KDIM + k0 + q * 4) = o;
    } else {
        const float4 z = {0.f, 0.f, 0.f, 0.f};
        #pragma unroll
        for (int k = 0; k < 4; ++k) lrow[tid * 4 + k] = z;
        if (tid < 128) ctr[tid] = 0;
    }
}

// ---------------------------------------------------------------------------
// Kernel 1: fused qvk + score + pv via ordered work queue.
// ctr layout (ints): [0]=work, [1]=vcnt, [8..40)=qdone, [40..72)=kdone,
// [72..104)=sdone. Items: [0,512) Q/K tiles, [512,768) V tiles,
// [768,1296) score tiles, [1296,1936) pv items.
// Deadlock-free: items grabbed in order -> any spin target is already
// executing. Producers: per-thread __threadfence, barrier, thread0
// release-increment. Consumers: thread0 agent-acquire spin (L2-inv covers
// the block's subsequent data loads), barrier.
// ---------------------------------------------------------------------------
__global__ __launch_bounds__(256, 3) void attn(
    const unsigned short* __restrict__ Xb, const unsigned short* __restrict__ Wt,
    unsigned short* __restrict__ Qb, unsigned short* __restrict__ Kb,
    unsigned short* __restrict__ Vt, unsigned short* __restrict__ Sb,
    float* __restrict__ lrow, float* __restrict__ out, int* __restrict__ ctr)
{
    __shared__ __align__(16) unsigned short lds[16384];
    __shared__ int t_sh;
    int* work  = ctr;
    int* vcnt  = ctr + 1;
    int* qdone = ctr + 8;
    int* kdone = ctr + 40;
    int* sdone = ctr + 72;

    const int tid  = threadIdx.x;
    const int wave = tid >> 6, lane = tid & 63;
    const int lr = lane & 15, quad = lane >> 4;
    const int wm = (wave >> 1) * 64, wn = (wave & 1) * 64;

    while (true) {
        __syncthreads();                 // protect t_sh before overwrite
        if (tid == 0)
            t_sh = __hip_atomic_fetch_add(work, 1, __ATOMIC_RELAXED,
                                          __HIP_MEMORY_SCOPE_AGENT);
        __syncthreads();
        const int t = t_sh;
        if (t >= N_TOTAL) return;

        if (t < N_QVK) {
            // ---- qvk tile: Q/K first (t<512), then V ----
            int m, nb;
            if (t < 512) { m = t >> 4; int r = t & 15; nb = (r < 8) ? r : r + 8; }
            else         { int u = t - 512; m = u >> 3; nb = 8 + (u & 7); }
            const int m0 = m * 128, n0 = nb * 128;
            f32x4 acc[4][4];
            zero_acc(acc);
            mfma_db(Xb + m0 * KDIM, KDIM, Wt + n0 * KDIM, KDIM, KDIM, lds, acc);
            __syncthreads();
            unsigned short* lw = lds + wave * 2560;
            const int region = n0 >> 10;
            const int nloc = n0 & 1023;
            if (region == 0)
                store_rows_bf16(acc, Qb + (m0 + wm) * KDIM + nloc + wn, KDIM, lw, lane);
            else if (region == 2)
                store_rows_bf16(acc, Kb + (m0 + wm) * KDIM + nloc + wn, KDIM, lw, lane);
            else
                store_cols_bf16(acc, Vt + (nloc + wn) * SEQ + m0 + wm, lw, lane);
            __threadfence();
            __syncthreads();
            if (tid == 0) {
                int* d = (region == 0) ? &qdone[m] : (region == 2) ? &kdone[m] : vcnt;
                __hip_atomic_fetch_add(d, 1, __ATOMIC_RELEASE, __HIP_MEMORY_SCOPE_AGENT);
            }
        } else if (t < N_QVK + N_SCORE) {
            // ---- score tile ----
            const int b = t - N_QVK;
            int bm = (int)((sqrtf(8.f * (float)b + 1.f) - 1.f) * 0.5f);
            while ((bm + 1) * (bm + 2) / 2 <= b) ++bm;
            while (bm * (bm + 1) / 2 > b) --bm;
            const int bn = b - bm * (bm + 1) / 2;
            const int m0 = bm * 128, n0 = bn * 128;
            if (tid == 0) {
                while (__hip_atomic_load(&qdone[bm], __ATOMIC_ACQUIRE,
                                         __HIP_MEMORY_SCOPE_AGENT) < 8 ||
                       __hip_atomic_load(&kdone[bn], __ATOMIC_ACQUIRE,
                                         __HIP_MEMORY_SCOPE_AGENT) < 8)
                    __builtin_amdgcn_s_sleep(2);
            }
            __syncthreads();

            f32x4 acc[4][4];
            zero_acc(acc);
            mfma_db(Qb + m0 * KDIM, KDIM, Kb + n0 * KDIM, KDIM, KDIM, lds, acc);
            #pragma unroll
            for (int i = 0; i < 4; ++i)
                #pragma unroll
                for (int j = 0; j < 4; ++j)
                    #pragma unroll
                    for (int r = 0; r < 4; ++r) {
                        float v = __expf(acc[i][j][r] * 0.03125f);
                        if (bm == bn) {
                            int row = wm + 16 * i + quad * 4 + r;
                            int col = wn + 16 * j + lr;
                            if (col > row) v = 0.f;
                        }
                        acc[i][j][r] = v;
                    }
            __syncthreads();
            store_rows_bf16(acc, Sb + (m0 + wm) * SEQ + n0 + wn, SEQ, lds + wave * 2560, lane);
            #pragma unroll
            for (int i = 0; i < 4; ++i)
                #pragma unroll
                for (int r = 0; r < 4; ++r) {
                    float s = acc[i][0][r] + acc[i][1][r] + acc[i][2][r] + acc[i][3][r];
                    s += __shfl_xor(s, 1, 16);
                    s += __shfl_xor(s, 2, 16);
                    s += __shfl_xor(s, 4, 16);
                    s += __shfl_xor(s, 8, 16);
                    if (lr == 0)
                        atomicAdd(&lrow[m0 + wm + 16 * i + quad * 4 + r], s);
                }
            __threadfence();
            __syncthreads();
            if (tid == 0)
                __hip_atomic_fetch_add(&sdone[bm], 1, __ATOMIC_RELEASE,
                                       __HIP_MEMORY_SCOPE_AGENT);
        } else {
            // ---- pv item: out = (P @ V)/l, split-K chunks of 1024 ----
            const int p = t - N_QVK - N_SCORE;
            const int n0 = (p & 7) * 128;
            const int y = p >> 3;           // 0..79
            int m, c;
            if (y < 8)       { m = y;                 c = 0; }
            else if (y < 24) { m = 8 + (y - 8) / 2;   c = (y - 8) % 2; }
            else if (y < 48) { m = 16 + (y - 24) / 3; c = (y - 24) % 3; }
            else             { m = 24 + (y - 48) / 4; c = (y - 48) % 4; }
            const int m0 = m * 128;
            const int kstart = c * 1024;
            const int kend = min((m + 1) * 128, kstart + 1024);
            const int nchunks = (m >> 3) + 1;
            if (tid == 0) {
                while (__hip_atomic_load(&sdone[m], __ATOMIC_ACQUIRE,
                                         __HIP_MEMORY_SCOPE_AGENT) < m + 1 ||
                       __hip_atomic_load(vcnt, __ATOMIC_ACQUIRE,
                                         __HIP_MEMORY_SCOPE_AGENT) < 256)
                    __builtin_amdgcn_s_sleep(2);
            }
            __syncthreads();

            f32x4 acc[4][4];
            zero_acc(acc);
            mfma_db(Sb + m0 * SEQ + kstart, SEQ, Vt + n0 * SEQ + kstart, SEQ,
                    kend - kstart, lds, acc);
            #pragma unroll
            for (int i = 0; i < 4; ++i) {
                const int rbase = m0 + wm + 16 * i + quad * 4;
                const float4 l4 = *(const float4*)(lrow + rbase);
                float inv[4] = {1.0f / l4.x, 1.0f / l4.y, 1.0f / l4.z, 1.0f / l4.w};
                #pragma unroll
                for (int j = 0; j < 4; ++j) {
                    const int col = n0 + wn + 16 * j + lr;
                    if (nchunks == 1) {
                        #pragma unroll
                        for (int r = 0; r < 4; ++r)
                            out[(rbase + r) * KDIM + col] = acc[i][j][r] * inv[r];
                    } else {
                        #pragma unroll
                        for (int r = 0; r < 4; ++r)
                            atomicAdd(&out[(rbase + r) * KDIM + col], acc[i][j][r] * inv[r]);
                    }
                }
            }
        }
    }
}

// ---------------------------------------------------------------------------
extern "C" void kernel_launch(void* const* d_in, const int* in_sizes, int n_in,
                              void* d_out, int out_size, void* d_ws, size_t ws_size,
                              hipStream_t stream) {
    const float* x = (const float*)d_in[0];   // [4096][1024]
    const float* W = (const float*)d_in[1];   // [1024][3072]
    float* out = (float*)d_out;               // [4096][1024]
    char* ws = (char*)d_ws;

    unsigned short* Xb = (unsigned short*)(ws);                     //  8 MiB
    unsigned short* Wt = (unsigned short*)(ws + 8388608);           //  6 MiB
    unsigned short* Qb = (unsigned short*)(ws + 14680064);          //  8 MiB
    unsigned short* Kb = (unsigned short*)(ws + 23068672);          //  8 MiB
    unsigned short* Vt = (unsigned short*)(ws + 31457280);          //  8 MiB
    unsigned short* Sb = (unsigned short*)(ws + 39845888);          // 32 MiB
    float*        lrow = (float*)(ws + 73400320);                   // 16 KiB
    // counters hide in Sb's never-touched upper-tri corner: row 0, cols 3840+
    int*           ctr = (int*)(ws + 39845888 + 3840 * 2);          // 512 B

    prep<<<11265, 256, 0, stream>>>(x, Xb, W, Wt, (float4*)out, (float4*)lrow, ctr);
    attn<<<768, 256, 0, stream>>>(Xb, Wt, Qb, Kb, Vt, Sb, lrow, out, ctr);
}

// Round 12
// 204.469 us; speedup vs baseline: 2.6807x; 2.6807x over previous
//
#include <hip/hip_runtime.h>

#define SEQ 4096
#define KDIM 1024
#define NQKV 3072
#define BK 32

typedef __bf16 bf16x8 __attribute__((ext_vector_type(8)));
typedef float  f32x4  __attribute__((ext_vector_type(4)));

#define WAITV(n) asm volatile("s_waitcnt vmcnt(" #n ")" ::: "memory")
#define BAR()    asm volatile("s_barrier" ::: "memory")

__device__ __forceinline__ unsigned short f2b(float f) {
    unsigned int u = __float_as_uint(f);
    u += 0x7FFFu + ((u >> 16) & 1u);   // round-to-nearest-even
    return (unsigned short)(u >> 16);
}

__device__ __forceinline__ void gld_lds16(const unsigned short* g, unsigned short* l) {
    __builtin_amdgcn_global_load_lds(
        (const __attribute__((address_space(1))) void*)g,
        (__attribute__((address_space(3))) void*)l, 16, 0, 0);
}

// ---------------------------------------------------------------------------
// Shared pieces: XOR-swizzled staging + fragment reads + MFMA compute.
// ---------------------------------------------------------------------------
__device__ __forceinline__ void stage_tiles(
    const unsigned short* Ag, int lda, const unsigned short* Bg, int ldb,
    int k0, unsigned short* sA, unsigned short* sB, int wave, int lane)
{
    #pragma unroll
    for (int i = 0; i < 2; ++i) {
        int c = wave * 128 + i * 64 + lane;        // chunk id 0..511
        int row = c >> 2, slot = c & 3;
        int p = slot ^ ((row >> 1) & 3);           // XOR-swizzled piece
        gld_lds16(Ag + row * lda + k0 + p * 8, sA + (wave * 2 + i) * 512);
        gld_lds16(Bg + row * ldb + k0 + p * 8, sB + (wave * 2 + i) * 512);
    }
}

__device__ __forceinline__ const unsigned short* frag_addr(
    const unsigned short* s, int row, int quad)
{
    return s + row * 32 + (quad ^ ((row >> 1) & 3)) * 8;
}

__device__ __forceinline__ void compute_tile(
    const unsigned short* sA, const unsigned short* sB, f32x4 acc[4][4],
    int wm, int wn, int lr, int quad)
{
    bf16x8 af[4], bq[4];
    #pragma unroll
    for (int i = 0; i < 4; ++i)
        af[i] = *(const bf16x8*)frag_addr(sA, wm + 16 * i + lr, quad);
    #pragma unroll
    for (int j = 0; j < 4; ++j)
        bq[j] = *(const bf16x8*)frag_addr(sB, wn + 16 * j + lr, quad);
    #pragma unroll
    for (int i = 0; i < 4; ++i)
        #pragma unroll
        for (int j = 0; j < 4; ++j)
            acc[i][j] = __builtin_amdgcn_mfma_f32_16x16x32_bf16(af[i], bq[j], acc[i][j], 0, 0, 0);
}

// 3-stage vmcnt-gated pipe (48 KB LDS) — K=1024 GEMMs (qvk, score). [R7]
__device__ __forceinline__ void mfma_pipe3(
    const unsigned short* Ag, int lda, const unsigned short* Bg, int ldb,
    int kLen, unsigned short* lds, f32x4 acc[4][4])
{
    const int tid  = threadIdx.x;
    const int wave = tid >> 6, lane = tid & 63;
    const int lr   = lane & 15, quad = lane >> 4;
    const int wm   = (wave >> 1) * 64, wn = (wave & 1) * 64;
    const int niter = kLen >> 5;

    #pragma unroll
    for (int s = 0; s < 2; ++s)
        if (s < niter)
            stage_tiles(Ag, lda, Bg, ldb, s * BK,
                        lds + s * 8192, lds + s * 8192 + 4096, wave, lane);

    #pragma unroll 1
    for (int k = 0; k < niter; ++k) {
        if (k + 1 < niter) WAITV(4);    // stage k done; k+1 stays in flight
        else               WAITV(0);
        BAR();
        if (k + 2 < niter) {
            const int s = (k + 2) % 3;
            stage_tiles(Ag, lda, Bg, ldb, (k + 2) * BK,
                        lds + s * 8192, lds + s * 8192 + 4096, wave, lane);
        }
        const int c = k % 3;
        compute_tile(lds + c * 8192, lds + c * 8192 + 4096, acc, wm, wn, lr, quad);
    }
}

// 4-stage vmcnt-gated pipe (64 KB LDS, 3 tiles in flight) — pv A/B test.
// R5 ran this with the WRONG grid orientation (confounded); now paired with
// the proven x=n,y=pair pv grid. 2 blocks/CU x 3 in-flight = 6 tile-loads/CU,
// enough to cover the ~900cy HBM-miss latency per 200cy of compute.
__device__ __forceinline__ void mfma_pipe4(
    const unsigned short* Ag, int lda, const unsigned short* Bg, int ldb,
    int kLen, unsigned short* lds, f32x4 acc[4][4])
{
    const int tid  = threadIdx.x;
    const int wave = tid >> 6, lane = tid & 63;
    const int lr   = lane & 15, quad = lane >> 4;
    const int wm   = (wave >> 1) * 64, wn = (wave & 1) * 64;
    const int niter = kLen >> 5;

    #pragma unroll
    for (int s = 0; s < 3; ++s)
        if (s < niter)
            stage_tiles(Ag, lda, Bg, ldb, s * BK,
                        lds + s * 8192, lds + s * 8192 + 4096, wave, lane);

    #pragma unroll 1
    for (int k = 0; k < niter; ++k) {
        if (k + 2 < niter)      WAITV(8);   // stage k done; k+1,k+2 in flight
        else if (k + 1 < niter) WAITV(4);
        else                    WAITV(0);
        BAR();
        if (k + 3 < niter) {
            const int s = (k + 3) & 3;
            stage_tiles(Ag, lda, Bg, ldb, (k + 3) * BK,
                        lds + s * 8192, lds + s * 8192 + 4096, wave, lane);
        }
        const int c = k & 3;
        compute_tile(lds + c * 8192, lds + c * 8192 + 4096, acc, wm, wn, lr, quad);
    }
}

__device__ __forceinline__ void zero_acc(f32x4 acc[4][4]) {
    const f32x4 z = {0.f, 0.f, 0.f, 0.f};
    #pragma unroll
    for (int i = 0; i < 4; ++i)
        #pragma unroll
        for (int j = 0; j < 4; ++j) acc[i][j] = z;
}

// ---------------------------------------------------------------------------
// Epilogues: wave-private LDS restage -> 16B coalesced bf16 stores.
// ---------------------------------------------------------------------------
__device__ __forceinline__ void store_rows_bf16(
    f32x4 acc[4][4], unsigned short* Cw, int ld, unsigned short* lw, int lane)
{
    const int lr = lane & 15, quad = lane >> 4;
    #pragma unroll
    for (int i = 0; i < 4; ++i) {
        #pragma unroll
        for (int j = 0; j < 4; ++j)
            #pragma unroll
            for (int r = 0; r < 4; ++r)
                lw[(quad * 4 + r) * 72 + j * 16 + lr] = f2b(acc[i][j][r]);
        #pragma unroll
        for (int t = 0; t < 2; ++t) {
            int chunk = t * 64 + lane;
            int rl = chunk >> 3, c8 = chunk & 7;
            uint4 v = *(const uint4*)(lw + rl * 72 + c8 * 8);
            *(uint4*)(Cw + (16 * i + rl) * ld + c8 * 8) = v;
        }
    }
}

__device__ __forceinline__ void store_cols_bf16(
    f32x4 acc[4][4], unsigned short* Vw, unsigned short* lw, int lane)
{
    const int lr = lane & 15, quad = lane >> 4;
    #pragma unroll
    for (int ip = 0; ip < 2; ++ip) {
        #pragma unroll
        for (int ii = 0; ii < 2; ++ii)
            #pragma unroll
            for (int j = 0; j < 4; ++j)
                #pragma unroll
                for (int r = 0; r < 4; ++r)
                    lw[(j * 16 + lr) * 40 + ii * 16 + quad * 4 + r] = f2b(acc[ip * 2 + ii][j][r]);
        #pragma unroll
        for (int t = 0; t < 4; ++t) {
            int chunk = t * 64 + lane;
            int col = chunk >> 2, c8 = chunk & 3;
            uint4 v = *(const uint4*)(lw + col * 40 + c8 * 8);
            *(uint4*)(Vw + col * SEQ + ip * 32 + c8 * 8) = v;
        }
    }
}

// ---------------------------------------------------------------------------
// Kernel 0: fused prep. [0,4096): x->bf16; [4096,8192): zero d_out;
// [8192,11264): W transpose (ushort4 stores); block 11264: zero lrow.
// ---------------------------------------------------------------------------
__global__ __launch_bounds__(256) void prep(
    const float* __restrict__ x, unsigned short* __restrict__ Xb,
    const float* __restrict__ W, unsigned short* __restrict__ Wt,
    float4* __restrict__ out, float4* __restrict__ lrow)
{
    __shared__ float tile[32][33];
    const int b = blockIdx.x, tid = threadIdx.x;
    if (b < 4096) {
        int i = (b * 256 + tid) * 4;
        float4 v = *(const float4*)(x + i);
        ushort4 o;
        o.x = f2b(v.x); o.y = f2b(v.y); o.z = f2b(v.z); o.w = f2b(v.w);
        *(ushort4*)(Xb + i) = o;
    } else if (b < 8192) {
        const float4 z = {0.f, 0.f, 0.f, 0.f};
        out[(b - 4096) * 256 + tid] = z;
    } else if (b < 11264) {
        const int bb = b - 8192;
        const int n0 = (bb % 96) * 32, k0 = (bb / 96) * 32;
        const int c = tid & 31, r0 = tid >> 5;
        #pragma unroll
        for (int r = r0; r < 32; r += 8)
            tile[r][c] = W[(k0 + r) * NQKV + n0 + c];   // tile[k][n]
        __syncthreads();
        const int n = tid >> 3, q = tid & 7;
        ushort4 o;
        o.x = f2b(tile[q * 4 + 0][n]);
        o.y = f2b(tile[q * 4 + 1][n]);
        o.z = f2b(tile[q * 4 + 2][n]);
        o.w = f2b(tile[q * 4 + 3][n]);
        *(ushort4*)(Wt + (n0 + n) * KDIM + k0 + q * 4) = o;
    } else {
        const float4 z = {0.f, 0.f, 0.f, 0.f};
        #pragma unroll
        for (int k = 0; k < 4; ++k) lrow[tid * 4 + k] = z;
    }
}

// ---------------------------------------------------------------------------
// Kernel 1: qvk = Xb @ Wt^T -> Q rows, K rows, V transposed (Vt[d][s])
// ---------------------------------------------------------------------------
__global__ __launch_bounds__(256) void qvk_gemm(
    const unsigned short* __restrict__ Xb, const unsigned short* __restrict__ Wt,
    unsigned short* __restrict__ Qb, unsigned short* __restrict__ Kb,
    unsigned short* __restrict__ Vt)
{
    __shared__ __align__(16) unsigned short lds[24576];   // 48 KiB
    const int m0 = blockIdx.x * 128;
    const int n0 = blockIdx.y * 128;
    f32x4 acc[4][4];
    zero_acc(acc);
    mfma_pipe3(Xb + m0 * KDIM, KDIM, Wt + n0 * KDIM, KDIM, KDIM, lds, acc);
    __syncthreads();

    const int lane = threadIdx.x & 63, wave = threadIdx.x >> 6;
    const int wm = (wave >> 1) * 64, wn = (wave & 1) * 64;
    unsigned short* lw = lds + wave * 2560;
    const int region = n0 >> 10;
    const int nloc = n0 & 1023;
    if (region == 0)
        store_rows_bf16(acc, Qb + (m0 + wm) * KDIM + nloc + wn, KDIM, lw, lane);
    else if (region == 2)
        store_rows_bf16(acc, Kb + (m0 + wm) * KDIM + nloc + wn, KDIM, lw, lane);
    else
        store_cols_bf16(acc, Vt + (nloc + wn) * SEQ + m0 + wm, lw, lane);
}

// ---------------------------------------------------------------------------
// Kernel 2: fused score+exp. P = exp((Q@K^T)/32) causal (no max-sub: |s|<=16
// by Cauchy-Schwarz). Grid (bm=32, bn=32), early-exit bn>bm. [R7 config]
// ---------------------------------------------------------------------------
__global__ __launch_bounds__(256) void score_exp_gemm(
    const unsigned short* __restrict__ Qb, const unsigned short* __restrict__ Kb,
    unsigned short* __restrict__ Sb, float* __restrict__ lrow)
{
    __shared__ __align__(16) unsigned short lds[24576];
    const int bm = blockIdx.x, bn = blockIdx.y;
    if (bn > bm) return;
    const int m0 = bm * 128, n0 = bn * 128;

    f32x4 acc[4][4];
    zero_acc(acc);
    mfma_pipe3(Qb + m0 * KDIM, KDIM, Kb + n0 * KDIM, KDIM, KDIM, lds, acc);

    const int lane = threadIdx.x & 63, wave = threadIdx.x >> 6;
    const int lr = lane & 15, quad = lane >> 4;
    const int wm = (wave >> 1) * 64, wn = (wave & 1) * 64;
    #pragma unroll
    for (int i = 0; i < 4; ++i)
        #pragma unroll
        for (int j = 0; j < 4; ++j)
            #pragma unroll
            for (int r = 0; r < 4; ++r) {
                float v = __expf(acc[i][j][r] * 0.03125f);
                if (bm == bn) {
                    int row = wm + 16 * i + quad * 4 + r;
                    int col = wn + 16 * j + lr;
                    if (col > row) v = 0.f;
                }
                acc[i][j][r] = v;
            }
    __syncthreads();
    store_rows_bf16(acc, Sb + (m0 + wm) * SEQ + n0 + wn, SEQ, lds + wave * 2560, lane);
    #pragma unroll
    for (int i = 0; i < 4; ++i)
        #pragma unroll
        for (int r = 0; r < 4; ++r) {
            float s = acc[i][0][r] + acc[i][1][r] + acc[i][2][r] + acc[i][3][r];
            s += __shfl_xor(s, 1, 16);
            s += __shfl_xor(s, 2, 16);
            s += __shfl_xor(s, 4, 16);
            s += __shfl_xor(s, 8, 16);
            if (lr == 0)
                atomicAdd(&lrow[m0 + wm + 16 * i + quad * 4 + r], s);
        }
}

// ---------------------------------------------------------------------------
// Kernel 3: out = (P @ V) / l, split-K 1024-chunks (atomic depth <=4).
// Grid x=n(8), y=pair(80): proven atomic-locality orientation. 4-stage pipe.
// ---------------------------------------------------------------------------
__global__ __launch_bounds__(256) void pv_gemm(
    const unsigned short* __restrict__ Sb, const unsigned short* __restrict__ Vt,
    const float* __restrict__ lrow, float* __restrict__ out)
{
    __shared__ __align__(16) unsigned short lds[32768];   // 64 KiB
    const int n0 = blockIdx.x * 128;
    const int y = blockIdx.y;               // 0..79
    int m, c;
    if (y < 8)       { m = y;                 c = 0; }
    else if (y < 24) { m = 8 + (y - 8) / 2;   c = (y - 8) % 2; }
    else if (y < 48) { m = 16 + (y - 24) / 3; c = (y - 24) % 3; }
    else             { m = 24 + (y - 48) / 4; c = (y - 48) % 4; }
    const int m0 = m * 128;
    const int kstart = c * 1024;
    const int kend = min((m + 1) * 128, kstart + 1024);
    const int nchunks = (m >> 3) + 1;

    f32x4 acc[4][4];
    zero_acc(acc);
    mfma_pipe4(Sb + m0 * SEQ + kstart, SEQ, Vt + n0 * SEQ + kstart, SEQ,
               kend - kstart, lds, acc);

    const int lane = threadIdx.x & 63, wave = threadIdx.x >> 6;
    const int lr = lane & 15, quad = lane >> 4;
    const int wm = (wave >> 1) * 64, wn = (wave & 1) * 64;
    #pragma unroll
    for (int i = 0; i < 4; ++i) {
        const int rbase = m0 + wm + 16 * i + quad * 4;
        const float4 l4 = *(const float4*)(lrow + rbase);
        float inv[4] = {1.0f / l4.x, 1.0f / l4.y, 1.0f / l4.z, 1.0f / l4.w};
        #pragma unroll
        for (int j = 0; j < 4; ++j) {
            const int col = n0 + wn + 16 * j + lr;
            if (nchunks == 1) {
                #pragma unroll
                for (int r = 0; r < 4; ++r)
                    out[(rbase + r) * KDIM + col] = acc[i][j][r] * inv[r];
            } else {
                #pragma unroll
                for (int r = 0; r < 4; ++r)
                    atomicAdd(&out[(rbase + r) * KDIM + col], acc[i][j][r] * inv[r]);
            }
        }
    }
}

// ---------------------------------------------------------------------------
extern "C" void kernel_launch(void* const* d_in, const int* in_sizes, int n_in,
                              void* d_out, int out_size, void* d_ws, size_t ws_size,
                              hipStream_t stream) {
    const float* x = (const float*)d_in[0];   // [4096][1024]
    const float* W = (const float*)d_in[1];   // [1024][3072]
    float* out = (float*)d_out;               // [4096][1024]
    char* ws = (char*)d_ws;

    unsigned short* Xb = (unsigned short*)(ws);                     //  8 MiB
    unsigned short* Wt = (unsigned short*)(ws + 8388608);           //  6 MiB
    unsigned short* Qb = (unsigned short*)(ws + 14680064);          //  8 MiB
    unsigned short* Kb = (unsigned short*)(ws + 23068672);          //  8 MiB
    unsigned short* Vt = (unsigned short*)(ws + 31457280);          //  8 MiB
    unsigned short* Sb = (unsigned short*)(ws + 39845888);          // 32 MiB
    float*        lrow = (float*)(ws + 73400320);                   // 16 KiB

    prep          <<<11265, 256, 0, stream>>>(x, Xb, W, Wt, (float4*)out, (float4*)lrow);
    qvk_gemm      <<<dim3(SEQ / 128, NQKV / 128), 256, 0, stream>>>(Xb, Wt, Qb, Kb, Vt);
    score_exp_gemm<<<dim3(SEQ / 128, SEQ / 128), 256, 0, stream>>>(Qb, Kb, Sb, lrow);
    pv_gemm       <<<dim3(KDIM / 128, 80), 256, 0, stream>>>(Sb, Vt, lrow, out);
}